// Round 4
// baseline (85.247 us; speedup 1.0000x reference)
//
#include <hip/hip_runtime.h>
#include <hip/hip_fp16.h>

#define TPB 256
#define NBLK 2048
#define AW 68            // apron row stride in half2 (src x = -2..65)
#define AH 67            // apron rows              (src y = -2..64)
#define ANE (AH * AW)    // 4556 half2 = 18,224 B LDS -> 8 blocks/CU, 32 waves/CU

__device__ __forceinline__ int refl(int v) {
    // reflect-101; here v in [-2, 65] -> result in [0, 63]
    v = v < 0 ? -v : v;
    return v > 63 ? 126 - v : v;
}

__device__ __forceinline__ void cubic_w(float t, float w[4]) {
    // A = -0.75 ; s = 1-t
    float s = 1.0f - t;
    float t2 = t * t;
    float s2 = s * s;
    w[0] = -0.75f * t * s2;                       // A*t*s^2
    w[1] = 1.25f * (t2 * t) - 2.25f * t2 + 1.0f;  // (A+2)t^3-(A+3)t^2+1
    w[2] = 1.25f * (s2 * s) - 2.25f * s2 + 1.0f;
    w[3] = -0.75f * s * t2;
}

__global__ __launch_bounds__(TPB) void deformation_field_kernel(
        const float4* __restrict__ coord4,   // (y0,x0,y1,x1) = two coords per float4
        const float*  __restrict__ depl,     // (2,64,64) f32
        const float*  __restrict__ mask,     // (2,64,64) f32
        float4* __restrict__ out4,           // two (c0,c1) fp32 results per float4
        int n_pairs)
{
    // Apron image: img[(y+2)*AW + (x+2)] = masked img at reflected (y,x),
    // channels packed as half2 (c0,c1). fp32 math downstream.
    __shared__ __half2 img[ANE];

    for (int t = threadIdx.x; t < ANE; t += TPB) {
        int y  = t / AW;            // 0..66
        int x  = t - y * AW;        // 0..67
        int sy = refl(y - 2);
        int sx = refl(x - 2);
        int o  = (sy << 6) + sx;
        float c0 = depl[o]        * mask[o];
        float c1 = depl[4096 + o] * mask[4096 + o];
        img[t] = __floats2half2_rn(c0, c1);
    }
    __syncthreads();

    const int stride = gridDim.x * TPB;
    for (int p = blockIdx.x * TPB + threadIdx.x; p < n_pairs; p += stride) {
        float4 c = coord4[p];
        float res[4];
        #pragma unroll
        for (int q = 0; q < 2; ++q) {
            // crop = 1/64; scale = 0.5*(64-1) = 31.5
            float gy = (q ? c.z : c.x) - 0.015625f;
            float gx = (q ? c.w : c.y) - 0.015625f;
            float ix = (gx + 1.0f) * 31.5f;
            float iy = (gy + 1.0f) * 31.5f;
            float fx0 = floorf(ix);
            float fy0 = floorf(iy);
            float tx = ix - fx0;
            float ty = iy - fy0;
            int jx = (int)fx0;      // in [-1, 62]
            int jy = (int)fy0;      // in [-1, 62]

            float wx[4], wy[4];
            cubic_w(tx, wx);
            cubic_w(ty, wy);

            // first tap (jy-1, jx-1) -> apron index (jy+1)*AW + (jx+1).
            // 16 taps = one vaddr + constant dword offsets {i*68 + j} <= 207.
            const __half2* base = &img[(jy + 1) * AW + (jx + 1)];

            float a0 = 0.0f, a1 = 0.0f;
            #pragma unroll
            for (int i = 0; i < 4; ++i) {
                float2 v0 = __half22float2(base[i * AW + 0]);
                float2 v1 = __half22float2(base[i * AW + 1]);
                float2 v2 = __half22float2(base[i * AW + 2]);
                float2 v3 = __half22float2(base[i * AW + 3]);
                float r0 = wx[0] * v0.x;
                float r1 = wx[0] * v0.y;
                r0 = fmaf(wx[1], v1.x, r0);
                r1 = fmaf(wx[1], v1.y, r1);
                r0 = fmaf(wx[2], v2.x, r0);
                r1 = fmaf(wx[2], v2.y, r1);
                r0 = fmaf(wx[3], v3.x, r0);
                r1 = fmaf(wx[3], v3.y, r1);
                a0 = fmaf(wy[i], r0, a0);
                a1 = fmaf(wy[i], r1, a1);
            }
            res[2 * q + 0] = a0;
            res[2 * q + 1] = a1;
        }
        out4[p] = make_float4(res[0], res[1], res[2], res[3]);
    }
}

extern "C" void kernel_launch(void* const* d_in, const int* in_sizes, int n_in,
                              void* d_out, int out_size, void* d_ws, size_t ws_size,
                              hipStream_t stream) {
    const float4* coord4 = (const float4*)d_in[0];  // (B,2) f32
    const float*  depl   = (const float*)d_in[1];   // (2,64,64) f32
    const float*  mask   = (const float*)d_in[2];   // (2,64,64) f32
    float4* out4 = (float4*)d_out;                  // (B,2) f32 -> B/2 float4

    int n_pairs = in_sizes[0] / 4;  // B/2
    int grid = NBLK;
    int max_grid = (n_pairs + TPB - 1) / TPB;
    if (grid > max_grid) grid = max_grid;

    deformation_field_kernel<<<grid, TPB, 0, stream>>>(coord4, depl, mask, out4, n_pairs);
}

// Round 5
// 82.094 us; speedup vs baseline: 1.0384x; 1.0384x over previous
//
#include <hip/hip_runtime.h>
#include <hip/hip_fp16.h>

#define TPB 256
#define NBLK 1024        // 4 blocks/CU @ 36.4 KB LDS -> all resident
#define AW 68            // apron row stride in half2 (src x = -2..65)
#define AH 67            // apron rows              (src y = -2..64)
#define ANE (AH * AW)    // 4556 half2 per copy; two parity copies = 36,448 B LDS

__device__ __forceinline__ int refl(int v) {
    // reflect-101; here v in [-2, 65] -> result in [0, 63]
    v = v < 0 ? -v : v;
    return v > 63 ? 126 - v : v;
}

__device__ __forceinline__ void cubic_w(float t, float w[4]) {
    // A = -0.75 ; s = 1-t
    float s = 1.0f - t;
    float t2 = t * t;
    float s2 = s * s;
    w[0] = -0.75f * t * s2;                       // A*t*s^2
    w[1] = 1.25f * (t2 * t) - 2.25f * t2 + 1.0f;  // (A+2)t^3-(A+3)t^2+1
    w[2] = 1.25f * (s2 * s) - 2.25f * s2 + 1.0f;
    w[3] = -0.75f * s * t2;
}

__global__ __launch_bounds__(TPB) void deformation_field_kernel(
        const float4* __restrict__ coord4,   // (y0,x0,y1,x1) = two coords per float4
        const float*  __restrict__ depl,     // (2,64,64) f32
        const float*  __restrict__ mask,     // (2,64,64) f32
        float4* __restrict__ out4,           // two (c0,c1) fp32 results per float4
        int n_pairs)
{
    // Two parity copies of the fp16 apron image so any 4-tap row window
    // (16 B) starts 8B-aligned -> one ds_read2_b64 per row.
    //   img_e[t]   = apron[t]
    //   img_o[t-1] = apron[t]   (shifted by one half2)
    __shared__ __align__(16) __half2 img_e[ANE];
    __shared__ __align__(16) __half2 img_o[ANE];

    for (int t = threadIdx.x; t < ANE; t += TPB) {
        int y  = t / AW;            // 0..66
        int x  = t - y * AW;        // 0..67
        int sy = refl(y - 2);
        int sx = refl(x - 2);
        int o  = (sy << 6) + sx;
        float c0 = depl[o]        * mask[o];
        float c1 = depl[4096 + o] * mask[4096 + o];
        __half2 v = __floats2half2_rn(c0, c1);
        img_e[t] = v;
        if (t > 0) img_o[t - 1] = v;
    }
    __syncthreads();

    const int stride = gridDim.x * TPB;
    for (int p = blockIdx.x * TPB + threadIdx.x; p < n_pairs; p += stride) {
        float4 c = coord4[p];
        float res[4];
        #pragma unroll
        for (int q = 0; q < 2; ++q) {
            // crop = 1/64; scale = 0.5*(64-1) = 31.5
            float gy = (q ? c.z : c.x) - 0.015625f;
            float gx = (q ? c.w : c.y) - 0.015625f;
            float ix = (gx + 1.0f) * 31.5f;
            float iy = (gy + 1.0f) * 31.5f;
            float fx0 = floorf(ix);
            float fy0 = floorf(iy);
            float tx = ix - fx0;
            float ty = iy - fy0;
            int jx = (int)fx0;      // in [-1, 62]
            int jy = (int)fy0;      // in [-1, 62]

            float wx[4], wy[4];
            cubic_w(tx, wx);
            cubic_w(ty, wy);

            // first tap index in apron (half2 units)
            int b = (jy + 1) * AW + (jx + 1);
            // pick parity copy so the row window is 8B-aligned
            const uint2* base = (b & 1)
                ? (const uint2*)img_o + ((b - 1) >> 1)
                : (const uint2*)img_e + (b >> 1);

            float a0 = 0.0f, a1 = 0.0f;
            #pragma unroll
            for (int i = 0; i < 4; ++i) {
                // one 16B row: 4 half2 taps, constant offsets i*34 + {0,1}
                uint2 lo = base[i * 34];
                uint2 hi = base[i * 34 + 1];
                float2 v0 = __half22float2(*(const __half2*)&lo.x);
                float2 v1 = __half22float2(*(const __half2*)&lo.y);
                float2 v2 = __half22float2(*(const __half2*)&hi.x);
                float2 v3 = __half22float2(*(const __half2*)&hi.y);
                float r0 = wx[0] * v0.x;
                float r1 = wx[0] * v0.y;
                r0 = fmaf(wx[1], v1.x, r0);
                r1 = fmaf(wx[1], v1.y, r1);
                r0 = fmaf(wx[2], v2.x, r0);
                r1 = fmaf(wx[2], v2.y, r1);
                r0 = fmaf(wx[3], v3.x, r0);
                r1 = fmaf(wx[3], v3.y, r1);
                a0 = fmaf(wy[i], r0, a0);
                a1 = fmaf(wy[i], r1, a1);
            }
            res[2 * q + 0] = a0;
            res[2 * q + 1] = a1;
        }
        out4[p] = make_float4(res[0], res[1], res[2], res[3]);
    }
}

extern "C" void kernel_launch(void* const* d_in, const int* in_sizes, int n_in,
                              void* d_out, int out_size, void* d_ws, size_t ws_size,
                              hipStream_t stream) {
    const float4* coord4 = (const float4*)d_in[0];  // (B,2) f32
    const float*  depl   = (const float*)d_in[1];   // (2,64,64) f32
    const float*  mask   = (const float*)d_in[2];   // (2,64,64) f32
    float4* out4 = (float4*)d_out;                  // (B,2) f32 -> B/2 float4

    int n_pairs = in_sizes[0] / 4;  // B/2
    int grid = NBLK;
    int max_grid = (n_pairs + TPB - 1) / TPB;
    if (grid > max_grid) grid = max_grid;

    deformation_field_kernel<<<grid, TPB, 0, stream>>>(coord4, depl, mask, out4, n_pairs);
}